// Round 14
// baseline (90.483 us; speedup 1.0000x reference)
//
#include <hip/hip_runtime.h>

typedef __attribute__((ext_vector_type(8))) short short8;
typedef __attribute__((ext_vector_type(4))) float f32x4;
typedef __attribute__((ext_vector_type(4))) unsigned short us4;

constexpr int NB = 8, NC = 256, IH = 64, IW = 96;
constexpr int PATCH = 21, RAD = 10;
constexpr int WIN = 28;                  // window j-width (tile j=8 + 20)
constexpr int KC = 32, NKS = NC / KC;    // channel chunking
constexpr int PLANE = IH * IW;
constexpr int PH = IH + 2 * RAD, PW = IW + 2 * RAD;   // 84 x 116 padded x2
// 16x8 pixel tile, window 36 rows split into two 18-row halves per block
constexpr int NPOS = 512;                // 18*28=504 positions padded to 512
constexpr int NBCH = NPOS * 4;           // 2048 B-chunks / K-step
constexpr int NACH = 512;                // A: 128 px * 32ch / 8per-chunk
constexpr int NCHUNK = NBCH + NACH;      // 2560 chunks = 5 slots x 512 thr
constexpr int ASTR = IH * IW * KC;       // per-ks stride in x1k (elements)
constexpr int BSTR = PH * PW * KC;       // per-ks stride in x2k (elements)
constexpr size_t X1T_ELEMS = (size_t)NB * NKS * ASTR;   // 12.58M
constexpr size_t X2P_ELEMS = (size_t)NB * NKS * BSTR;   // 19.96M
constexpr int GSTR = 129;                // G row stride (floats)

__device__ __forceinline__ unsigned short f2bf(float f) {
  unsigned u = __builtin_bit_cast(unsigned, f);
  u += 0x7fffu + ((u >> 16) & 1u);       // RNE
  return (unsigned short)(u >> 16);
}

// ---- pre-pass 1: x1 NCHW fp32 -> K-major [b][ks][i][j][32] bf16 (validated) ----
__global__ __launch_bounds__(256) void x1_to_kmajor(
    const float* __restrict__ src, unsigned short* __restrict__ dst) {
  __shared__ float lsf[32 * 97];
  const int blk = blockIdx.x;            // b*512 + i*8 + ct
  const int ct = blk & 7, i = (blk >> 3) & 63, b = blk >> 9;
  const int c0 = ct * 32, t = threadIdx.x;
  const float* sp = src + ((size_t)b * NC + c0) * PLANE + (size_t)i * IW;
#pragma unroll
  for (int k = 0; k < 12; ++k) {
    int idx = k * 256 + t;
    int c = idx / 96, j = idx - c * 96;
    lsf[c * 97 + j] = sp[(size_t)c * PLANE + j];
  }
  __syncthreads();
  unsigned short* dp = dst + (((size_t)(b * NKS + ct) * IH + i) * IW) * KC;
#pragma unroll
  for (int k = 0; k < 3; ++k) {
    int o = k * 256 + t;
    int j = o >> 3, cq = o & 7;
    us4 v = {f2bf(lsf[(cq * 4 + 0) * 97 + j]), f2bf(lsf[(cq * 4 + 1) * 97 + j]),
             f2bf(lsf[(cq * 4 + 2) * 97 + j]), f2bf(lsf[(cq * 4 + 3) * 97 + j])};
    *(us4*)&dp[(size_t)j * KC + cq * 4] = v;
  }
}

// ---- pre-pass 2: x2 NCHW fp32 -> K-major halo-padded [b][ks][84][116][32] (validated) ----
__global__ __launch_bounds__(256) void x2_to_kmajor_pad(
    const float* __restrict__ src, unsigned short* __restrict__ dst) {
  __shared__ float lsf[32 * 97];
  const int blk = blockIdx.x;            // b*(84*8) + i*8 + ct
  const int ct = blk & 7, i = (blk >> 3) % PH, b = blk / (PH * 8);
  const int c0 = ct * 32, t = threadIdx.x;
  const int isrc = i - RAD;
  const bool rowok = (unsigned)isrc < (unsigned)IH;
  if (rowok) {
    const float* sp = src + ((size_t)b * NC + c0) * PLANE + (size_t)isrc * IW;
#pragma unroll
    for (int k = 0; k < 12; ++k) {
      int idx = k * 256 + t;
      int c = idx / 96, j = idx - c * 96;
      lsf[c * 97 + j] = sp[(size_t)c * PLANE + j];
    }
  }
  __syncthreads();
  unsigned short* dp = dst + (((size_t)(b * NKS + ct) * PH + i) * PW) * KC;
#pragma unroll
  for (int k = 0; k < 4; ++k) {
    int o = k * 256 + t;
    if (o < PW * 8) {
      int j = o >> 3, cq = o & 7;
      int jsrc = j - RAD;
      us4 v = {0, 0, 0, 0};
      if (rowok && (unsigned)jsrc < (unsigned)IW)
        v = us4{f2bf(lsf[(cq * 4 + 0) * 97 + jsrc]), f2bf(lsf[(cq * 4 + 1) * 97 + jsrc]),
                f2bf(lsf[(cq * 4 + 2) * 97 + jsrc]), f2bf(lsf[(cq * 4 + 3) * 97 + jsrc])};
      *(us4*)&dp[(size_t)j * KC + cq * 4] = v;
    }
  }
}

#define MFMA4(CC, BF)                                                               \
    acc[0][CC] = __builtin_amdgcn_mfma_f32_16x16x32_bf16(af0, BF, acc[0][CC], 0, 0, 0); \
    acc[1][CC] = __builtin_amdgcn_mfma_f32_16x16x32_bf16(af1, BF, acc[1][CC], 0, 0, 0); \
    acc[2][CC] = __builtin_amdgcn_mfma_f32_16x16x32_bf16(af2, BF, acc[2][CC], 0, 0, 0); \
    acc[3][CC] = __builtin_amdgcn_mfma_f32_16x16x32_bf16(af3, BF, acc[3][CC], 0, 0, 0);

// ---- main: 16x8 tile x half-window, 8-wave triple-buffered, 4-phase compute ----
// R13-validated staging/vmcnt skeleton; COMPUTE split into 4 barrier-delimited
// phases (T3): prefetch next 2 B-frags -> setprio(1) -> 8 MFMAs -> setprio(0)
// -> s_barrier. Extra uniform barriers are strictly conservative (no new races).
__global__ __launch_bounds__(512, 2) void corr_half(
    const unsigned short* __restrict__ x1k, const unsigned short* __restrict__ x2k,
    float* __restrict__ out) {
  __shared__ __attribute__((aligned(16))) unsigned short ls[3 * NCHUNK * 8];  // 122880 B

  const int t = threadIdx.x, lane = t & 63, wv = t >> 6;   // wv 0..7
  const int bid = blockIdx.x;
  const int b = bid & 7;                 // batch -> XCD locality
  const int tile = bid >> 3;             // 0..95
  const int v = tile & 1;                // window half (rows 18v..18v+17)
  const int tt = tile >> 1;              // 0..47
  const int ti = tt / 12, tj = tt % 12;
  const int i0 = 16 * ti, j0 = 8 * tj;
  const int mg = wv >> 2;                // M-group: frags 4mg..4mg+3
  const int cg = wv & 3;                 // col-group: tiles 8cg..8cg+7 (exact)
  const int cbeg = 8 * cg;
  const int qk = lane >> 4, lr = lane & 15;

  const unsigned short* x1b = x1k + (size_t)b * NKS * ASTR;
  const unsigned short* x2b = x2k + (size_t)b * NKS * BSTR;

  // 5 stage slots x 512 thr: slots 0-3 B (2048 chunks, swizzled), slot 4 A (512)
  const unsigned short* srcp[5];
#pragma unroll
  for (int it = 0; it < 5; ++it) {
    int q = it * 512 + t;
    if (q < NBCH) {                       // B: invert slot swizzle (validated form)
      int w = ((q >> 3) << 1) | (((q >> 2) ^ (q >> 4)) & 1);
      int c4 = (q & 3) ^ (w & 3);
      int wd = (w >= 504) ? (w - 504) : w;      // 8 dummy positions replicate
      int wi = wd / WIN, wj = wd - wi * WIN;
      srcp[it] = x2b + ((size_t)(i0 + 18 * v + wi) * PW + (j0 + wj)) * KC + c4 * 8;
    } else {                              // A: same inverse over qa 0..511
      int qa = q - NBCH;
      int m = ((qa >> 3) << 1) | (((qa >> 2) ^ (qa >> 4)) & 1);
      int c4 = (qa & 3) ^ (m & 3);
      srcp[it] = x1b + ((size_t)(i0 + (m >> 3)) * IW + (j0 + (m & 7))) * KC + c4 * 8;
    }
  }

  f32x4 acc[4][8];
#pragma unroll
  for (int a = 0; a < 4; ++a)
#pragma unroll
    for (int cc = 0; cc < 8; ++cc) acc[a][cc] = (f32x4){0.f, 0.f, 0.f, 0.f};

#define STAGE(BUF, KS)                                                              \
  {                                                                                 \
    unsigned short* lb = &ls[(BUF) * NCHUNK * 8];                                   \
    _Pragma("unroll")                                                               \
    for (int it = 0; it < 5; ++it)                                                  \
      __builtin_amdgcn_global_load_lds(                                             \
          (const void*)(srcp[it] + (size_t)(KS) * (it < 4 ? BSTR : ASTR)),          \
          (void*)(lb + (it * 512 + wv * 64) * 8), 16, 0, 0);                        \
  }

#define LDB(CC) (*(const short8*)(lb + (((4 * (16 * (cbeg + (CC)) + lr) + qk) ^ (lr & 7))) * 8))

#define COMPUTE(BUF)                                                                \
  {                                                                                 \
    const unsigned short* lb = &ls[(BUF) * NCHUNK * 8];                             \
    short8 af0 = *(const short8*)(lb + (NBCH + ((64 * (4 * mg + 0) + 4 * lr + qk) ^ (lr & 7))) * 8); \
    short8 af1 = *(const short8*)(lb + (NBCH + ((64 * (4 * mg + 1) + 4 * lr + qk) ^ (lr & 7))) * 8); \
    short8 af2 = *(const short8*)(lb + (NBCH + ((64 * (4 * mg + 2) + 4 * lr + qk) ^ (lr & 7))) * 8); \
    short8 af3 = *(const short8*)(lb + (NBCH + ((64 * (4 * mg + 3) + 4 * lr + qk) ^ (lr & 7))) * 8); \
    short8 b0 = LDB(0), b1 = LDB(1);                                                \
    short8 n0, n1;                                                                  \
    /* phase 0 */                                                                   \
    n0 = LDB(2); n1 = LDB(3);                                                       \
    __builtin_amdgcn_s_setprio(1);                                                  \
    MFMA4(0, b0) MFMA4(1, b1)                                                       \
    __builtin_amdgcn_s_setprio(0);                                                  \
    asm volatile("s_barrier" ::: "memory");                                         \
    b0 = n0; b1 = n1;                                                               \
    /* phase 1 */                                                                   \
    n0 = LDB(4); n1 = LDB(5);                                                       \
    __builtin_amdgcn_s_setprio(1);                                                  \
    MFMA4(2, b0) MFMA4(3, b1)                                                       \
    __builtin_amdgcn_s_setprio(0);                                                  \
    asm volatile("s_barrier" ::: "memory");                                         \
    b0 = n0; b1 = n1;                                                               \
    /* phase 2 */                                                                   \
    n0 = LDB(6); n1 = LDB(7);                                                       \
    __builtin_amdgcn_s_setprio(1);                                                  \
    MFMA4(4, b0) MFMA4(5, b1)                                                       \
    __builtin_amdgcn_s_setprio(0);                                                  \
    asm volatile("s_barrier" ::: "memory");                                         \
    b0 = n0; b1 = n1;                                                               \
    /* phase 3 */                                                                   \
    __builtin_amdgcn_s_setprio(1);                                                  \
    MFMA4(6, b0) MFMA4(7, b1)                                                       \
    __builtin_amdgcn_s_setprio(0);                                                  \
  }

  // prologue: stage ks=0,1
  STAGE(0, 0)
  STAGE(1, 1)

  // R5/R8/R13-validated ordering, uniform 5 loads/wave/stage:
  // steady in-flight after STAGE(ks+2) = 15 -> vmcnt(10) drains stage(ks).
#define ITER(KS, VM)                                           \
  if ((KS) < 6) STAGE(((KS) + 2) % 3, (KS) + 2)                \
  asm volatile("s_waitcnt vmcnt(" #VM ")" ::: "memory");       \
  asm volatile("s_barrier" ::: "memory");                      \
  COMPUTE((KS) % 3)                                            \
  asm volatile("s_barrier" ::: "memory");

  ITER(0, 10)
  ITER(1, 10)
  ITER(2, 10)
  ITER(3, 10)
  ITER(4, 10)
  ITER(5, 10)
  ITER(6, 5)
  ITER(7, 0)
#undef ITER
#undef COMPUTE
#undef LDB
#undef STAGE

  // ---- epilogue: G transpose in 3 row-passes of 168 (R13-validated) ----
  float* gf = (float*)ls;
#pragma unroll
  for (int p = 0; p < 3; ++p) {
    __syncthreads();                     // prior reads (staging or pass p-1) done
    const int R0 = 168 * p;
#pragma unroll
    for (int a = 0; a < 4; ++a)
#pragma unroll
      for (int cc = 0; cc < 8; ++cc) {
        int n = 16 * (cbeg + cc) + lr;
        if (n >= R0 && n < R0 + 168) {
          int rl = n - R0;
          int sm = 4 * (4 * mg + a) + qk;          // m-granule 0..31
          float* gp = &gf[rl * GSTR + 4 * (sm ^ (rl & 7))];
          gp[0] = acc[a][cc][0]; gp[1] = acc[a][cc][1];
          gp[2] = acc[a][cc][2]; gp[3] = acc[a][cc][3];
        }
      }
    __syncthreads();
    int segs = 0;
#pragma unroll
    for (int kk = 0; kk < 6; ++kk) {
      int W = 18 * v + 6 * p + kk;
      int hi = W < 15 ? W : 15, lo = W - 20 > 0 ? W - 20 : 0;
      segs += hi - lo + 1;
    }
    segs *= 21;
    for (int s = t; s < segs; s += 512) {
      int pidx = s / 21, pj = s - pidx * 21;
      int k = 0, rem = pidx, stop = 0;
#pragma unroll
      for (int kk = 0; kk < 5; ++kk) {
        int W = 18 * v + 6 * p + kk;
        int hi = W < 15 ? W : 15, lo = W - 20 > 0 ? W - 20 : 0;
        int c = hi - lo + 1;
        int go = (!stop) && (rem >= c);
        rem -= go ? c : 0;
        k += go;
        stop |= !go;
      }
      int W = 18 * v + 6 * p + k;
      int lo = W - 20 > 0 ? W - 20 : 0;
      int ii = lo + rem;
      int pi = W - ii;
      int rl0 = 28 * k + pj;
      float g[8];
#pragma unroll
      for (int e = 0; e < 8; ++e) {
        int m = 8 * ii + e, row = rl0 + e;
        g[e] = gf[row * GSTR + 4 * ((m >> 2) ^ (row & 7)) + (m & 3)];
      }
      float* op = out + ((((size_t)b * PATCH + pi) * PATCH + pj) * IH + (i0 + ii)) * IW + j0;
      f32x4 v0 = {g[0], g[1], g[2], g[3]};
      f32x4 v1 = {g[4], g[5], g[6], g[7]};
      *(f32x4*)op = v0;
      *(f32x4*)(op + 4) = v1;
    }
  }
}

// ---------------- fallback (R1, validated): NCHW fp32 in-kernel ----------------
constexpr int LDKF = 40;
constexpr int NWINF = 784;
__global__ __launch_bounds__(512, 2) void corr_mfma_fb(
    const float* __restrict__ x1, const float* __restrict__ x2, float* __restrict__ out) {
  __shared__ __attribute__((aligned(16))) unsigned short lsA[64 * LDKF];
  __shared__ __attribute__((aligned(16))) unsigned short lsB[NWINF * LDKF];
  const int t = threadIdx.x;
  const int b = blockIdx.y;
  const int ti = blockIdx.x / 12, tj = blockIdx.x % 12;
  const int i0 = ti * 8, j0 = tj * 8;
  const int lane = t & 63, wv = t >> 6;
  const int mtp = wv >> 2, cg = wv & 3, cbeg = cg * 12;
  const int qk = lane >> 4, lr = lane & 15;
  f32x4 acc[2][13];
#pragma unroll
  for (int a = 0; a < 2; ++a)
#pragma unroll
    for (int cc = 0; cc < 13; ++cc) acc[a][cc] = (f32x4){0.f, 0.f, 0.f, 0.f};
  const int am = t & 63, ak4 = t >> 6;
  const int aii = am >> 3, ajj = am & 7;
  const float* x1p = x1 + ((size_t)b * NC + 4 * ak4) * PLANE + (size_t)(i0 + aii) * IW + (j0 + ajj);
  const float* x2b = x2 + (size_t)b * NC * PLANE;
  for (int ks = 0; ks < NKS; ++ks) {
    __syncthreads();
    {
      const float* p = x1p + (size_t)ks * KC * PLANE;
      us4 v = {f2bf(p[0]), f2bf(p[PLANE]), f2bf(p[2 * PLANE]), f2bf(p[3 * PLANE])};
      *(us4*)&lsA[am * LDKF + 4 * ak4] = v;
    }
    for (int w = t; w < NWINF; w += 512) {
      const int wi = w / WIN, wj = w - wi * WIN;
      const int gi = i0 - RAD + wi, gj = j0 - RAD + wj;
      const bool ok = ((unsigned)gi < (unsigned)IH) && ((unsigned)gj < (unsigned)IW);
      const float* p = x2b + ((size_t)(ks * KC) * IH + gi) * IW + gj;
      unsigned short* dst = &lsB[w * LDKF];
#pragma unroll
      for (int k4 = 0; k4 < 8; ++k4) {
        const float* q = p + (size_t)(4 * k4) * PLANE;
        us4 v = {f2bf(ok ? q[0] : 0.f), f2bf(ok ? q[PLANE] : 0.f),
                 f2bf(ok ? q[2 * PLANE] : 0.f), f2bf(ok ? q[3 * PLANE] : 0.f)};
        *(us4*)&dst[4 * k4] = v;
      }
    }
    __syncthreads();
    short8 a0 = *(const short8*)&lsA[(32 * mtp + lr) * LDKF + 8 * qk];
    short8 a1 = *(const short8*)&lsA[(32 * mtp + 16 + lr) * LDKF + 8 * qk];
#pragma unroll
    for (int cc = 0; cc < 13; ++cc) {
      const int wrow = 16 * (cbeg + cc) + lr;
      short8 bf = *(const short8*)&lsB[wrow * LDKF + 8 * qk];
      acc[0][cc] = __builtin_amdgcn_mfma_f32_16x16x32_bf16(a0, bf, acc[0][cc], 0, 0, 0);
      acc[1][cc] = __builtin_amdgcn_mfma_f32_16x16x32_bf16(a1, bf, acc[1][cc], 0, 0, 0);
    }
  }
#pragma unroll
  for (int a = 0; a < 2; ++a) {
    const int mb = 16 * (2 * mtp + a) + qk * 4;
#pragma unroll
    for (int cc = 0; cc < 13; ++cc) {
      if (cg > 0 && cc == 0) continue;
      const int n = 16 * (cbeg + cc) + lr;
      const int wi = n / WIN, wj = n - wi * WIN;
#pragma unroll
      for (int r = 0; r < 4; ++r) {
        const int m = mb + r;
        const int ii = m >> 3, jj = m & 7;
        const int pi = wi - ii, pj = wj - jj;
        if ((unsigned)pi < (unsigned)PATCH && (unsigned)pj < (unsigned)PATCH)
          out[((((size_t)b * PATCH + pi) * PATCH + pj) * IH + (i0 + ii)) * IW + (j0 + jj)] =
              acc[a][cc][r];
      }
    }
  }
}

extern "C" void kernel_launch(void* const* d_in, const int* in_sizes, int n_in,
                              void* d_out, int out_size, void* d_ws, size_t ws_size,
                              hipStream_t stream) {
  const float* x1 = (const float*)d_in[0];
  const float* x2 = (const float*)d_in[1];
  float* out = (float*)d_out;
  const size_t need = (X1T_ELEMS + X2P_ELEMS) * sizeof(unsigned short);  // ~65.1 MB
  if (ws_size >= need) {
    unsigned short* x1k = (unsigned short*)d_ws;
    unsigned short* x2k = x1k + X1T_ELEMS;
    x1_to_kmajor<<<NB * IH * 8, 256, 0, stream>>>(x1, x1k);
    x2_to_kmajor_pad<<<NB * PH * 8, 256, 0, stream>>>(x2, x2k);
    corr_half<<<NB * 96, 512, 0, stream>>>(x1k, x2k, out);
  } else {
    dim3 grid(96, NB);
    corr_mfma_fb<<<grid, 512, 0, stream>>>(x1, x2, out);
  }
}

// Round 15
// 84.666 us; speedup vs baseline: 1.0687x; 1.0687x over previous
//
#include <hip/hip_runtime.h>

typedef __attribute__((ext_vector_type(8))) short short8;
typedef __attribute__((ext_vector_type(4))) float f32x4;
typedef __attribute__((ext_vector_type(4))) unsigned short us4;

constexpr int NB = 8, NC = 256, IH = 64, IW = 96;
constexpr int PATCH = 21, RAD = 10;
constexpr int TI = 8, TJ = 8;            // pixel tile
constexpr int WIN = 28, NWIN = 784;      // x2 window per tile
constexpr int KC = 32, NKS = NC / KC;    // channel chunking
constexpr int PLANE = IH * IW;
constexpr int PH = IH + 2 * RAD, PW = IW + 2 * RAD;   // 84 x 116 padded x2
constexpr int NBCH = NWIN * 4;           // 3136 B-chunks (16B) per K-step
constexpr int NCHUNK = NBCH + 256;       // + 256 A-chunks = 3392
constexpr int ASTR = IH * IW * KC;       // per-ks stride in x1k (elements)
constexpr int BSTR = PH * PW * KC;       // per-ks stride in x2k (elements)
constexpr size_t X1T_ELEMS = (size_t)NB * NKS * ASTR;   // 12.58M
constexpr size_t X2P_ELEMS = (size_t)NB * NKS * BSTR;   // 19.96M
constexpr int GSTR = 65;                 // G-chunk m-stride (floats)
constexpr int X1BLKS = NB * IH * 8;      // 4096 prepass blocks for x1
constexpr int X2BLKS = NB * PH * 8;      // 5376 prepass blocks for x2

__device__ __forceinline__ unsigned short f2bf(float f) {
  unsigned u = __builtin_bit_cast(unsigned, f);
  u += 0x7fffu + ((u >> 16) & 1u);       // RNE
  return (unsigned short)(u >> 16);
}

// ---- merged pre-pass: one dispatch, x1 body (blocks < X1BLKS) + x2 body ----
// Both bodies verbatim from the R8-validated split kernels.
__global__ __launch_bounds__(256) void prepass_kmajor(
    const float* __restrict__ x1, const float* __restrict__ x2,
    unsigned short* __restrict__ x1k, unsigned short* __restrict__ x2k) {
  __shared__ float lsf[32 * 97];
  const int t = threadIdx.x;
  if (blockIdx.x < X1BLKS) {
    // ---- x1 NCHW fp32 -> K-major [b][ks][i][j][32] bf16 ----
    const int blk = blockIdx.x;          // b*512 + i*8 + ct
    const int ct = blk & 7, i = (blk >> 3) & 63, b = blk >> 9;
    const int c0 = ct * 32;
    const float* sp = x1 + ((size_t)b * NC + c0) * PLANE + (size_t)i * IW;
#pragma unroll
    for (int k = 0; k < 12; ++k) {
      int idx = k * 256 + t;
      int c = idx / 96, j = idx - c * 96;
      lsf[c * 97 + j] = sp[(size_t)c * PLANE + j];
    }
    __syncthreads();
    unsigned short* dp = x1k + (((size_t)(b * NKS + ct) * IH + i) * IW) * KC;
#pragma unroll
    for (int k = 0; k < 3; ++k) {        // 96 j x 8 cq -> contiguous 8B writes
      int o = k * 256 + t;
      int j = o >> 3, cq = o & 7;
      us4 v = {f2bf(lsf[(cq * 4 + 0) * 97 + j]), f2bf(lsf[(cq * 4 + 1) * 97 + j]),
               f2bf(lsf[(cq * 4 + 2) * 97 + j]), f2bf(lsf[(cq * 4 + 3) * 97 + j])};
      *(us4*)&dp[(size_t)j * KC + cq * 4] = v;
    }
  } else {
    // ---- x2 NCHW fp32 -> K-major halo-padded [b][ks][84][116][32], halo=0 ----
    const int blk = blockIdx.x - X1BLKS; // b*(84*8) + i*8 + ct
    const int ct = blk & 7, i = (blk >> 3) % PH, b = blk / (PH * 8);
    const int c0 = ct * 32;
    const int isrc = i - RAD;
    const bool rowok = (unsigned)isrc < (unsigned)IH;
    if (rowok) {
      const float* sp = x2 + ((size_t)b * NC + c0) * PLANE + (size_t)isrc * IW;
#pragma unroll
      for (int k = 0; k < 12; ++k) {
        int idx = k * 256 + t;
        int c = idx / 96, j = idx - c * 96;
        lsf[c * 97 + j] = sp[(size_t)c * PLANE + j];
      }
    }
    __syncthreads();
    unsigned short* dp = x2k + (((size_t)(b * NKS + ct) * PH + i) * PW) * KC;
#pragma unroll
    for (int k = 0; k < 4; ++k) {        // 116 j x 8 cq = 928 items
      int o = k * 256 + t;
      if (o < PW * 8) {
        int j = o >> 3, cq = o & 7;
        int jsrc = j - RAD;
        us4 v = {0, 0, 0, 0};
        if (rowok && (unsigned)jsrc < (unsigned)IW)
          v = us4{f2bf(lsf[(cq * 4 + 0) * 97 + jsrc]), f2bf(lsf[(cq * 4 + 1) * 97 + jsrc]),
                  f2bf(lsf[(cq * 4 + 2) * 97 + jsrc]), f2bf(lsf[(cq * 4 + 3) * 97 + jsrc])};
        *(us4*)&dp[(size_t)j * KC + cq * 4] = v;
      }
    }
  }
}

// ---- main: 8-wave triple-buffered gload_lds pipeline (R8, best-validated) ----
// Each wave computes ALL 4 M-tiles for its 7 col-tiles: every staged B
// fragment is ds_read ONCE. Byte-identical to the R8 kernel (main 64.5 us).
__global__ __launch_bounds__(512, 2) void corr_pipe8(
    const unsigned short* __restrict__ x1k, const unsigned short* __restrict__ x2k,
    float* __restrict__ out) {
  __shared__ __attribute__((aligned(16))) unsigned short ls[3 * NCHUNK * 8];  // 162816 B

  const int t = threadIdx.x, lane = t & 63, wv = t >> 6;   // wv 0..7
  const int bid = blockIdx.x;
  const int b = bid & 7;                 // batch -> XCD locality
  const int tile = bid >> 3;
  const int ti = tile / 12, tj = tile - ti * 12;
  const int i0 = ti * TI, j0 = tj * TJ;
  const int cbeg = 6 * wv;               // 7 col-tiles/wave; overlap tiles bitwise-identical
  const int qk = lane >> 4, lr = lane & 15;

  const unsigned short* x1b = x1k + (size_t)b * NKS * ASTR;
  const unsigned short* x2b = x2k + (size_t)b * NKS * BSTR;

  // per-thread ks=0 source addresses for the 7 stage slots (q = it*512 + t)
  const unsigned short* srcp[7];
#pragma unroll
  for (int it = 0; it < 7; ++it) {
    int q = it * 512 + t;
    if (q < NBCH) {                       // B chunk: invert slot swizzle
      int w = ((q >> 3) << 1) | (((q >> 2) ^ (q >> 4)) & 1);
      int c4 = (q & 3) ^ (w & 3);
      int wi = w / WIN, wj = w - wi * WIN;
      srcp[it] = x2b + ((size_t)(i0 + wi) * PW + (j0 + wj)) * KC + c4 * 8;
    } else {                              // A chunk: same inverse on qa
      int qa = (q - NBCH) & 255;
      int m = ((qa >> 3) << 1) | (((qa >> 2) ^ (qa >> 4)) & 1);
      int c4 = (qa & 3) ^ (m & 3);
      srcp[it] = x1b + ((size_t)(i0 + (m >> 3)) * IW + (j0 + (m & 7))) * KC + c4 * 8;
    }
  }

  f32x4 acc[4][7];
#pragma unroll
  for (int a = 0; a < 4; ++a)
#pragma unroll
    for (int cc = 0; cc < 7; ++cc) acc[a][cc] = (f32x4){0.f, 0.f, 0.f, 0.f};

#define STAGE(BUF, KS)                                                              \
  {                                                                                 \
    unsigned short* lb = &ls[(BUF) * NCHUNK * 8];                                   \
    _Pragma("unroll")                                                               \
    for (int it = 0; it < 6; ++it)                                                  \
      __builtin_amdgcn_global_load_lds(                                             \
          (const void*)(srcp[it] + (size_t)(KS) * BSTR),                            \
          (void*)(lb + (it * 512 + wv * 64) * 8), 16, 0, 0);                        \
    if (wv < 5)                                                                     \
      __builtin_amdgcn_global_load_lds(                                             \
          (const void*)(srcp[6] + (size_t)(KS) * (wv == 0 ? BSTR : ASTR)),          \
          (void*)(lb + (3072 + wv * 64) * 8), 16, 0, 0);                            \
  }

#define COMPUTE(BUF)                                                                \
  {                                                                                 \
    const unsigned short* lb = &ls[(BUF) * NCHUNK * 8];                             \
    short8 af0 = *(const short8*)(lb + (NBCH + ((4 * (lr) + qk) ^ (lr & 7))) * 8);        \
    short8 af1 = *(const short8*)(lb + (NBCH + ((4 * (16 + lr) + qk) ^ (lr & 7))) * 8);   \
    short8 af2 = *(const short8*)(lb + (NBCH + ((4 * (32 + lr) + qk) ^ (lr & 7))) * 8);   \
    short8 af3 = *(const short8*)(lb + (NBCH + ((4 * (48 + lr) + qk) ^ (lr & 7))) * 8);   \
    _Pragma("unroll")                                                               \
    for (int cc = 0; cc < 7; ++cc) {                                                \
      int wrow = 16 * (cbeg + cc) + lr;                                             \
      int slot = (4 * wrow + qk) ^ (lr & 7);                                        \
      short8 bf = *(const short8*)(lb + slot * 8);                                  \
      acc[0][cc] = __builtin_amdgcn_mfma_f32_16x16x32_bf16(af0, bf, acc[0][cc], 0, 0, 0); \
      acc[1][cc] = __builtin_amdgcn_mfma_f32_16x16x32_bf16(af1, bf, acc[1][cc], 0, 0, 0); \
      acc[2][cc] = __builtin_amdgcn_mfma_f32_16x16x32_bf16(af2, bf, acc[2][cc], 0, 0, 0); \
      acc[3][cc] = __builtin_amdgcn_mfma_f32_16x16x32_bf16(af3, bf, acc[3][cc], 0, 0, 0); \
    }                                                                               \
  }

  // prologue: stage ks=0,1
  STAGE(0, 0)
  STAGE(1, 1)

  // Validated R5/R8 ordering: drain own stage(ks) loads BEFORE barrier (RAW);
  // barrier after COMPUTE protects the buffer restaged next iter (WAR).
#define ITER(KS, VM)                                           \
  if ((KS) < 6) STAGE(((KS) + 2) % 3, (KS) + 2)                \
  asm volatile("s_waitcnt vmcnt(" #VM ")" ::: "memory");       \
  asm volatile("s_barrier" ::: "memory");                      \
  COMPUTE((KS) % 3)                                            \
  asm volatile("s_barrier" ::: "memory");

  ITER(0, 12)
  ITER(1, 12)
  ITER(2, 12)
  ITER(3, 12)
  ITER(4, 12)
  ITER(5, 12)
  ITER(6, 6)
  ITER(7, 0)
#undef ITER
#undef COMPUTE
#undef STAGE

  // ---- epilogue: LDS diagonal transpose -> coalesced 32B row-segment stores ----
  // (R7/R8-validated structure; 512 threads, acc[4][7], m = 16a + 4qk + r)
  float* gf = (float*)ls;
#pragma unroll
  for (int ch = 0; ch < 2; ++ch) {
    __syncthreads();                     // full drain: staging reads/writes done
    const int n0 = ch ? 384 : 0;
#pragma unroll
    for (int a = 0; a < 4; ++a)
#pragma unroll
      for (int cc = 0; cc < 7; ++cc) {
        int ccg = cbeg + cc;
        if (ch ? (ccg >= 24) : (ccg <= 24)) {
          int nl = 16 * ccg + lr - n0;
          int mb = 16 * a + 4 * qk;
          float* gp = &gf[nl * GSTR + mb];
          gp[0] = acc[a][cc][0]; gp[1] = acc[a][cc][1];
          gp[2] = acc[a][cc][2]; gp[3] = acc[a][cc][3];
        }
      }
    __syncthreads();
    // 1764 segments per chunk: s = pidx*21 + pj; pidx enumerates (ii,pi) pairs
    // ch0: ii-group k has 14-k pi's (pi=rem); ch1: 7+k pi's (pi=14-k+rem).
    for (int s = t; s < 1764; s += 512) {
      int pidx = s / 21, pj = s - pidx * 21;
      int ii = 0, rem = pidx, stop = 0;
#pragma unroll
      for (int k = 0; k < 7; ++k) {
        int cnt = ch ? (7 + k) : (14 - k);
        int go = (!stop) && (rem >= cnt);
        rem -= go ? cnt : 0;
        ii += go;
        stop |= !go;
      }
      int pi = ch ? (14 - ii + rem) : rem;
      int nl = 28 * (pi + ii) + pj - n0;
      int ms = 8 * ii;
      float g[8];
#pragma unroll
      for (int e = 0; e < 8; ++e) g[e] = gf[(nl + e) * GSTR + ms + e];
      float* op = out + ((((size_t)b * PATCH + pi) * PATCH + pj) * IH + (i0 + ii)) * IW + j0;
      f32x4 v0 = {g[0], g[1], g[2], g[3]};
      f32x4 v1 = {g[4], g[5], g[6], g[7]};
      *(f32x4*)op = v0;
      *(f32x4*)(op + 4) = v1;
    }
  }
}

// ---------------- fallback (R1, validated): NCHW fp32 in-kernel ----------------
constexpr int LDKF = 40;
__global__ __launch_bounds__(512, 2) void corr_mfma_fb(
    const float* __restrict__ x1, const float* __restrict__ x2, float* __restrict__ out) {
  __shared__ __attribute__((aligned(16))) unsigned short lsA[64 * LDKF];
  __shared__ __attribute__((aligned(16))) unsigned short lsB[NWIN * LDKF];
  const int t = threadIdx.x;
  const int b = blockIdx.y;
  const int ti = blockIdx.x / 12, tj = blockIdx.x % 12;
  const int i0 = ti * TI, j0 = tj * TJ;
  const int lane = t & 63, wv = t >> 6;
  const int mtp = wv >> 2, cg = wv & 3, cbeg = cg * 12;
  const int qk = lane >> 4, lr = lane & 15;
  f32x4 acc[2][13];
#pragma unroll
  for (int a = 0; a < 2; ++a)
#pragma unroll
    for (int cc = 0; cc < 13; ++cc) acc[a][cc] = (f32x4){0.f, 0.f, 0.f, 0.f};
  const int am = t & 63, ak4 = t >> 6;
  const int aii = am >> 3, ajj = am & 7;
  const float* x1p = x1 + ((size_t)b * NC + 4 * ak4) * PLANE + (size_t)(i0 + aii) * IW + (j0 + ajj);
  const float* x2b = x2 + (size_t)b * NC * PLANE;
  for (int ks = 0; ks < NKS; ++ks) {
    __syncthreads();
    {
      const float* p = x1p + (size_t)ks * KC * PLANE;
      us4 v = {f2bf(p[0]), f2bf(p[PLANE]), f2bf(p[2 * PLANE]), f2bf(p[3 * PLANE])};
      *(us4*)&lsA[am * LDKF + 4 * ak4] = v;
    }
    for (int w = t; w < NWIN; w += 512) {
      const int wi = w / WIN, wj = w - wi * WIN;
      const int gi = i0 - RAD + wi, gj = j0 - RAD + wj;
      const bool ok = ((unsigned)gi < (unsigned)IH) && ((unsigned)gj < (unsigned)IW);
      const float* p = x2b + ((size_t)(ks * KC) * IH + gi) * IW + gj;
      unsigned short* dst = &lsB[w * LDKF];
#pragma unroll
      for (int k4 = 0; k4 < 8; ++k4) {
        const float* q = p + (size_t)(4 * k4) * PLANE;
        us4 v = {f2bf(ok ? q[0] : 0.f), f2bf(ok ? q[PLANE] : 0.f),
                 f2bf(ok ? q[2 * PLANE] : 0.f), f2bf(ok ? q[3 * PLANE] : 0.f)};
        *(us4*)&dst[4 * k4] = v;
      }
    }
    __syncthreads();
    short8 a0 = *(const short8*)&lsA[(32 * mtp + lr) * LDKF + 8 * qk];
    short8 a1 = *(const short8*)&lsA[(32 * mtp + 16 + lr) * LDKF + 8 * qk];
#pragma unroll
    for (int cc = 0; cc < 13; ++cc) {
      const int wrow = 16 * (cbeg + cc) + lr;
      short8 bf = *(const short8*)&lsB[wrow * LDKF + 8 * qk];
      acc[0][cc] = __builtin_amdgcn_mfma_f32_16x16x32_bf16(a0, bf, acc[0][cc], 0, 0, 0);
      acc[1][cc] = __builtin_amdgcn_mfma_f32_16x16x32_bf16(a1, bf, acc[1][cc], 0, 0, 0);
    }
  }
#pragma unroll
  for (int a = 0; a < 2; ++a) {
    const int mb = 16 * (2 * mtp + a) + qk * 4;
#pragma unroll
    for (int cc = 0; cc < 13; ++cc) {
      if (cg > 0 && cc == 0) continue;
      const int n = 16 * (cbeg + cc) + lr;
      const int wi = n / WIN, wj = n - wi * WIN;
#pragma unroll
      for (int r = 0; r < 4; ++r) {
        const int m = mb + r;
        const int ii = m >> 3, jj = m & 7;
        const int pi = wi - ii, pj = wj - jj;
        if ((unsigned)pi < (unsigned)PATCH && (unsigned)pj < (unsigned)PATCH)
          out[((((size_t)b * PATCH + pi) * PATCH + pj) * IH + (i0 + ii)) * IW + (j0 + jj)] =
              acc[a][cc][r];
      }
    }
  }
}

extern "C" void kernel_launch(void* const* d_in, const int* in_sizes, int n_in,
                              void* d_out, int out_size, void* d_ws, size_t ws_size,
                              hipStream_t stream) {
  const float* x1 = (const float*)d_in[0];
  const float* x2 = (const float*)d_in[1];
  float* out = (float*)d_out;
  const size_t need = (X1T_ELEMS + X2P_ELEMS) * sizeof(unsigned short);  // ~65.1 MB
  if (ws_size >= need) {
    unsigned short* x1k = (unsigned short*)d_ws;
    unsigned short* x2k = x1k + X1T_ELEMS;
    prepass_kmajor<<<X1BLKS + X2BLKS, 256, 0, stream>>>(x1, x2, x1k, x2k);
    corr_pipe8<<<NB * 96, 512, 0, stream>>>(x1k, x2k, out);
  } else {
    dim3 grid(96, NB);
    corr_mfma_fb<<<grid, 512, 0, stream>>>(x1, x2, out);
  }
}

// Round 16
// 84.618 us; speedup vs baseline: 1.0693x; 1.0006x over previous
//
#include <hip/hip_runtime.h>

typedef __attribute__((ext_vector_type(8))) short short8;
typedef __attribute__((ext_vector_type(4))) float f32x4;
typedef __attribute__((ext_vector_type(4))) unsigned short us4;

constexpr int NB = 8, NC = 256, IH = 64, IW = 96;
constexpr int PATCH = 21, RAD = 10;
constexpr int TI = 8, TJ = 8;            // pixel tile
constexpr int WIN = 28, NWIN = 784;      // x2 window per tile
constexpr int KC = 32, NKS = NC / KC;    // channel chunking
constexpr int PLANE = IH * IW;
constexpr int PH = IH + 2 * RAD, PW = IW + 2 * RAD;   // 84 x 116 padded x2
constexpr int NBCH = NWIN * 4;           // 3136 B-chunks (16B) per K-step
constexpr int NCHUNK = NBCH + 256;       // + 256 A-chunks = 3392
constexpr int ASTR = IH * IW * KC;       // per-ks stride in x1k (elements)
constexpr int BSTR = PH * PW * KC;       // per-ks stride in x2k (elements)
constexpr size_t X1T_ELEMS = (size_t)NB * NKS * ASTR;   // 12.58M
constexpr size_t X2P_ELEMS = (size_t)NB * NKS * BSTR;   // 19.96M
constexpr int GSTR = 65;                 // G-chunk m-stride (floats)
constexpr int X1BLKS = NB * IH * 8;      // 4096 prepass blocks for x1
constexpr int X2BLKS = NB * PH * 8;      // 5376 prepass blocks for x2

__device__ __forceinline__ unsigned short f2bf(float f) {
  unsigned u = __builtin_bit_cast(unsigned, f);
  u += 0x7fffu + ((u >> 16) & 1u);       // RNE
  return (unsigned short)(u >> 16);
}

// ---- merged pre-pass: one dispatch, x1 body (blocks < X1BLKS) + x2 body ----
// R15-validated bodies with global reads vectorized to float4 (12 scalar ->
// 3x16B per thread); LDS stores stay scalar (97-stride keeps conflict-free
// reads; 16B LDS alignment impossible at stride 97 -- global txns were the cost).
__global__ __launch_bounds__(256) void prepass_kmajor(
    const float* __restrict__ x1, const float* __restrict__ x2,
    unsigned short* __restrict__ x1k, unsigned short* __restrict__ x2k) {
  __shared__ float lsf[32 * 97];
  const int t = threadIdx.x;
  if (blockIdx.x < X1BLKS) {
    // ---- x1 NCHW fp32 -> K-major [b][ks][i][j][32] bf16 ----
    const int blk = blockIdx.x;          // b*512 + i*8 + ct
    const int ct = blk & 7, i = (blk >> 3) & 63, b = blk >> 9;
    const int c0 = ct * 32;
    const float* sp = x1 + ((size_t)b * NC + c0) * PLANE + (size_t)i * IW;
#pragma unroll
    for (int k = 0; k < 3; ++k) {        // 768 float4: c = idx/24, j4 = idx%24
      int idx = k * 256 + t;
      int c = idx / 24, j4 = idx - c * 24;
      f32x4 v = *(const f32x4*)(sp + (size_t)c * PLANE + 4 * j4);
      float* lp = &lsf[c * 97 + 4 * j4];
      lp[0] = v[0]; lp[1] = v[1]; lp[2] = v[2]; lp[3] = v[3];
    }
    __syncthreads();
    unsigned short* dp = x1k + (((size_t)(b * NKS + ct) * IH + i) * IW) * KC;
#pragma unroll
    for (int k = 0; k < 3; ++k) {        // 96 j x 8 cq -> contiguous 8B writes
      int o = k * 256 + t;
      int j = o >> 3, cq = o & 7;
      us4 v = {f2bf(lsf[(cq * 4 + 0) * 97 + j]), f2bf(lsf[(cq * 4 + 1) * 97 + j]),
               f2bf(lsf[(cq * 4 + 2) * 97 + j]), f2bf(lsf[(cq * 4 + 3) * 97 + j])};
      *(us4*)&dp[(size_t)j * KC + cq * 4] = v;
    }
  } else {
    // ---- x2 NCHW fp32 -> K-major halo-padded [b][ks][84][116][32], halo=0 ----
    const int blk = blockIdx.x - X1BLKS; // b*(84*8) + i*8 + ct
    const int ct = blk & 7, i = (blk >> 3) % PH, b = blk / (PH * 8);
    const int c0 = ct * 32;
    const int isrc = i - RAD;
    const bool rowok = (unsigned)isrc < (unsigned)IH;
    if (rowok) {
      const float* sp = x2 + ((size_t)b * NC + c0) * PLANE + (size_t)isrc * IW;
#pragma unroll
      for (int k = 0; k < 3; ++k) {      // 768 float4
        int idx = k * 256 + t;
        int c = idx / 24, j4 = idx - c * 24;
        f32x4 v = *(const f32x4*)(sp + (size_t)c * PLANE + 4 * j4);
        float* lp = &lsf[c * 97 + 4 * j4];
        lp[0] = v[0]; lp[1] = v[1]; lp[2] = v[2]; lp[3] = v[3];
      }
    }
    __syncthreads();
    unsigned short* dp = x2k + (((size_t)(b * NKS + ct) * PH + i) * PW) * KC;
#pragma unroll
    for (int k = 0; k < 4; ++k) {        // 116 j x 8 cq = 928 items
      int o = k * 256 + t;
      if (o < PW * 8) {
        int j = o >> 3, cq = o & 7;
        int jsrc = j - RAD;
        us4 v = {0, 0, 0, 0};
        if (rowok && (unsigned)jsrc < (unsigned)IW)
          v = us4{f2bf(lsf[(cq * 4 + 0) * 97 + jsrc]), f2bf(lsf[(cq * 4 + 1) * 97 + jsrc]),
                  f2bf(lsf[(cq * 4 + 2) * 97 + jsrc]), f2bf(lsf[(cq * 4 + 3) * 97 + jsrc])};
        *(us4*)&dp[(size_t)j * KC + cq * 4] = v;
      }
    }
  }
}

// ---- main: 8-wave triple-buffered gload_lds pipeline (R8/R15, best-validated) ----
// Byte-identical to the R15 kernel (main 64.4 us, twice re-validated).
__global__ __launch_bounds__(512, 2) void corr_pipe8(
    const unsigned short* __restrict__ x1k, const unsigned short* __restrict__ x2k,
    float* __restrict__ out) {
  __shared__ __attribute__((aligned(16))) unsigned short ls[3 * NCHUNK * 8];  // 162816 B

  const int t = threadIdx.x, lane = t & 63, wv = t >> 6;   // wv 0..7
  const int bid = blockIdx.x;
  const int b = bid & 7;                 // batch -> XCD locality
  const int tile = bid >> 3;
  const int ti = tile / 12, tj = tile - ti * 12;
  const int i0 = ti * TI, j0 = tj * TJ;
  const int cbeg = 6 * wv;               // 7 col-tiles/wave; overlap tiles bitwise-identical
  const int qk = lane >> 4, lr = lane & 15;

  const unsigned short* x1b = x1k + (size_t)b * NKS * ASTR;
  const unsigned short* x2b = x2k + (size_t)b * NKS * BSTR;

  // per-thread ks=0 source addresses for the 7 stage slots (q = it*512 + t)
  const unsigned short* srcp[7];
#pragma unroll
  for (int it = 0; it < 7; ++it) {
    int q = it * 512 + t;
    if (q < NBCH) {                       // B chunk: invert slot swizzle
      int w = ((q >> 3) << 1) | (((q >> 2) ^ (q >> 4)) & 1);
      int c4 = (q & 3) ^ (w & 3);
      int wi = w / WIN, wj = w - wi * WIN;
      srcp[it] = x2b + ((size_t)(i0 + wi) * PW + (j0 + wj)) * KC + c4 * 8;
    } else {                              // A chunk: same inverse on qa
      int qa = (q - NBCH) & 255;
      int m = ((qa >> 3) << 1) | (((qa >> 2) ^ (qa >> 4)) & 1);
      int c4 = (qa & 3) ^ (m & 3);
      srcp[it] = x1b + ((size_t)(i0 + (m >> 3)) * IW + (j0 + (m & 7))) * KC + c4 * 8;
    }
  }

  f32x4 acc[4][7];
#pragma unroll
  for (int a = 0; a < 4; ++a)
#pragma unroll
    for (int cc = 0; cc < 7; ++cc) acc[a][cc] = (f32x4){0.f, 0.f, 0.f, 0.f};

#define STAGE(BUF, KS)                                                              \
  {                                                                                 \
    unsigned short* lb = &ls[(BUF) * NCHUNK * 8];                                   \
    _Pragma("unroll")                                                               \
    for (int it = 0; it < 6; ++it)                                                  \
      __builtin_amdgcn_global_load_lds(                                             \
          (const void*)(srcp[it] + (size_t)(KS) * BSTR),                            \
          (void*)(lb + (it * 512 + wv * 64) * 8), 16, 0, 0);                        \
    if (wv < 5)                                                                     \
      __builtin_amdgcn_global_load_lds(                                             \
          (const void*)(srcp[6] + (size_t)(KS) * (wv == 0 ? BSTR : ASTR)),          \
          (void*)(lb + (3072 + wv * 64) * 8), 16, 0, 0);                            \
  }

#define COMPUTE(BUF)                                                                \
  {                                                                                 \
    const unsigned short* lb = &ls[(BUF) * NCHUNK * 8];                             \
    short8 af0 = *(const short8*)(lb + (NBCH + ((4 * (lr) + qk) ^ (lr & 7))) * 8);        \
    short8 af1 = *(const short8*)(lb + (NBCH + ((4 * (16 + lr) + qk) ^ (lr & 7))) * 8);   \
    short8 af2 = *(const short8*)(lb + (NBCH + ((4 * (32 + lr) + qk) ^ (lr & 7))) * 8);   \
    short8 af3 = *(const short8*)(lb + (NBCH + ((4 * (48 + lr) + qk) ^ (lr & 7))) * 8);   \
    _Pragma("unroll")                                                               \
    for (int cc = 0; cc < 7; ++cc) {                                                \
      int wrow = 16 * (cbeg + cc) + lr;                                             \
      int slot = (4 * wrow + qk) ^ (lr & 7);                                        \
      short8 bf = *(const short8*)(lb + slot * 8);                                  \
      acc[0][cc] = __builtin_amdgcn_mfma_f32_16x16x32_bf16(af0, bf, acc[0][cc], 0, 0, 0); \
      acc[1][cc] = __builtin_amdgcn_mfma_f32_16x16x32_bf16(af1, bf, acc[1][cc], 0, 0, 0); \
      acc[2][cc] = __builtin_amdgcn_mfma_f32_16x16x32_bf16(af2, bf, acc[2][cc], 0, 0, 0); \
      acc[3][cc] = __builtin_amdgcn_mfma_f32_16x16x32_bf16(af3, bf, acc[3][cc], 0, 0, 0); \
    }                                                                               \
  }

  // prologue: stage ks=0,1
  STAGE(0, 0)
  STAGE(1, 1)

  // Validated R5/R8 ordering: drain own stage(ks) loads BEFORE barrier (RAW);
  // barrier after COMPUTE protects the buffer restaged next iter (WAR).
#define ITER(KS, VM)                                           \
  if ((KS) < 6) STAGE(((KS) + 2) % 3, (KS) + 2)                \
  asm volatile("s_waitcnt vmcnt(" #VM ")" ::: "memory");       \
  asm volatile("s_barrier" ::: "memory");                      \
  COMPUTE((KS) % 3)                                            \
  asm volatile("s_barrier" ::: "memory");

  ITER(0, 12)
  ITER(1, 12)
  ITER(2, 12)
  ITER(3, 12)
  ITER(4, 12)
  ITER(5, 12)
  ITER(6, 6)
  ITER(7, 0)
#undef ITER
#undef COMPUTE
#undef STAGE

  // ---- epilogue: LDS diagonal transpose -> coalesced 32B row-segment stores ----
  // (R7/R8-validated structure; 512 threads, acc[4][7], m = 16a + 4qk + r)
  float* gf = (float*)ls;
#pragma unroll
  for (int ch = 0; ch < 2; ++ch) {
    __syncthreads();                     // full drain: staging reads/writes done
    const int n0 = ch ? 384 : 0;
#pragma unroll
    for (int a = 0; a < 4; ++a)
#pragma unroll
      for (int cc = 0; cc < 7; ++cc) {
        int ccg = cbeg + cc;
        if (ch ? (ccg >= 24) : (ccg <= 24)) {
          int nl = 16 * ccg + lr - n0;
          int mb = 16 * a + 4 * qk;
          float* gp = &gf[nl * GSTR + mb];
          gp[0] = acc[a][cc][0]; gp[1] = acc[a][cc][1];
          gp[2] = acc[a][cc][2]; gp[3] = acc[a][cc][3];
        }
      }
    __syncthreads();
    // 1764 segments per chunk: s = pidx*21 + pj; pidx enumerates (ii,pi) pairs
    // ch0: ii-group k has 14-k pi's (pi=rem); ch1: 7+k pi's (pi=14-k+rem).
    for (int s = t; s < 1764; s += 512) {
      int pidx = s / 21, pj = s - pidx * 21;
      int ii = 0, rem = pidx, stop = 0;
#pragma unroll
      for (int k = 0; k < 7; ++k) {
        int cnt = ch ? (7 + k) : (14 - k);
        int go = (!stop) && (rem >= cnt);
        rem -= go ? cnt : 0;
        ii += go;
        stop |= !go;
      }
      int pi = ch ? (14 - ii + rem) : rem;
      int nl = 28 * (pi + ii) + pj - n0;
      int ms = 8 * ii;
      float g[8];
#pragma unroll
      for (int e = 0; e < 8; ++e) g[e] = gf[(nl + e) * GSTR + ms + e];
      float* op = out + ((((size_t)b * PATCH + pi) * PATCH + pj) * IH + (i0 + ii)) * IW + j0;
      f32x4 v0 = {g[0], g[1], g[2], g[3]};
      f32x4 v1 = {g[4], g[5], g[6], g[7]};
      *(f32x4*)op = v0;
      *(f32x4*)(op + 4) = v1;
    }
  }
}

// ---------------- fallback (R1, validated): NCHW fp32 in-kernel ----------------
constexpr int LDKF = 40;
__global__ __launch_bounds__(512, 2) void corr_mfma_fb(
    const float* __restrict__ x1, const float* __restrict__ x2, float* __restrict__ out) {
  __shared__ __attribute__((aligned(16))) unsigned short lsA[64 * LDKF];
  __shared__ __attribute__((aligned(16))) unsigned short lsB[NWIN * LDKF];
  const int t = threadIdx.x;
  const int b = blockIdx.y;
  const int ti = blockIdx.x / 12, tj = blockIdx.x % 12;
  const int i0 = ti * TI, j0 = tj * TJ;
  const int lane = t & 63, wv = t >> 6;
  const int mtp = wv >> 2, cg = wv & 3, cbeg = cg * 12;
  const int qk = lane >> 4, lr = lane & 15;
  f32x4 acc[2][13];
#pragma unroll
  for (int a = 0; a < 2; ++a)
#pragma unroll
    for (int cc = 0; cc < 13; ++cc) acc[a][cc] = (f32x4){0.f, 0.f, 0.f, 0.f};
  const int am = t & 63, ak4 = t >> 6;
  const int aii = am >> 3, ajj = am & 7;
  const float* x1p = x1 + ((size_t)b * NC + 4 * ak4) * PLANE + (size_t)(i0 + aii) * IW + (j0 + ajj);
  const float* x2b = x2 + (size_t)b * NC * PLANE;
  for (int ks = 0; ks < NKS; ++ks) {
    __syncthreads();
    {
      const float* p = x1p + (size_t)ks * KC * PLANE;
      us4 v = {f2bf(p[0]), f2bf(p[PLANE]), f2bf(p[2 * PLANE]), f2bf(p[3 * PLANE])};
      *(us4*)&lsA[am * LDKF + 4 * ak4] = v;
    }
    for (int w = t; w < NWIN; w += 512) {
      const int wi = w / WIN, wj = w - wi * WIN;
      const int gi = i0 - RAD + wi, gj = j0 - RAD + wj;
      const bool ok = ((unsigned)gi < (unsigned)IH) && ((unsigned)gj < (unsigned)IW);
      const float* p = x2b + ((size_t)(ks * KC) * IH + gi) * IW + gj;
      unsigned short* dst = &lsB[w * LDKF];
#pragma unroll
      for (int k4 = 0; k4 < 8; ++k4) {
        const float* q = p + (size_t)(4 * k4) * PLANE;
        us4 v = {f2bf(ok ? q[0] : 0.f), f2bf(ok ? q[PLANE] : 0.f),
                 f2bf(ok ? q[2 * PLANE] : 0.f), f2bf(ok ? q[3 * PLANE] : 0.f)};
        *(us4*)&dst[4 * k4] = v;
      }
    }
    __syncthreads();
    short8 a0 = *(const short8*)&lsA[(32 * mtp + lr) * LDKF + 8 * qk];
    short8 a1 = *(const short8*)&lsA[(32 * mtp + 16 + lr) * LDKF + 8 * qk];
#pragma unroll
    for (int cc = 0; cc < 13; ++cc) {
      const int wrow = 16 * (cbeg + cc) + lr;
      short8 bf = *(const short8*)&lsB[wrow * LDKF + 8 * qk];
      acc[0][cc] = __builtin_amdgcn_mfma_f32_16x16x32_bf16(a0, bf, acc[0][cc], 0, 0, 0);
      acc[1][cc] = __builtin_amdgcn_mfma_f32_16x16x32_bf16(a1, bf, acc[1][cc], 0, 0, 0);
    }
  }
#pragma unroll
  for (int a = 0; a < 2; ++a) {
    const int mb = 16 * (2 * mtp + a) + qk * 4;
#pragma unroll
    for (int cc = 0; cc < 13; ++cc) {
      if (cg > 0 && cc == 0) continue;
      const int n = 16 * (cbeg + cc) + lr;
      const int wi = n / WIN, wj = n - wi * WIN;
#pragma unroll
      for (int r = 0; r < 4; ++r) {
        const int m = mb + r;
        const int ii = m >> 3, jj = m & 7;
        const int pi = wi - ii, pj = wj - jj;
        if ((unsigned)pi < (unsigned)PATCH && (unsigned)pj < (unsigned)PATCH)
          out[((((size_t)b * PATCH + pi) * PATCH + pj) * IH + (i0 + ii)) * IW + (j0 + jj)] =
              acc[a][cc][r];
      }
    }
  }
}

extern "C" void kernel_launch(void* const* d_in, const int* in_sizes, int n_in,
                              void* d_out, int out_size, void* d_ws, size_t ws_size,
                              hipStream_t stream) {
  const float* x1 = (const float*)d_in[0];
  const float* x2 = (const float*)d_in[1];
  float* out = (float*)d_out;
  const size_t need = (X1T_ELEMS + X2P_ELEMS) * sizeof(unsigned short);  // ~65.1 MB
  if (ws_size >= need) {
    unsigned short* x1k = (unsigned short*)d_ws;
    unsigned short* x2k = x1k + X1T_ELEMS;
    prepass_kmajor<<<X1BLKS + X2BLKS, 256, 0, stream>>>(x1, x2, x1k, x2k);
    corr_pipe8<<<NB * 96, 512, 0, stream>>>(x1k, x2k, out);
  } else {
    dim3 grid(96, NB);
    corr_mfma_fb<<<grid, 512, 0, stream>>>(x1, x2, out);
  }
}